// Round 7
// baseline (1588.964 us; speedup 1.0000x reference)
//
#include <hip/hip_runtime.h>
#include <hip/hip_bf16.h>
#include <math.h>

#define NN 4000
#define TG 32
#define TT 16
#define FF 256
#define HH 384
#define GCOLS 1536
#define KCAT 640
#define EE 64000
#define D4 512

typedef __attribute__((ext_vector_type(8))) short short8;
typedef __attribute__((ext_vector_type(4))) float float4v;

static __device__ __forceinline__ float fsig(float x)  { return 1.0f / (1.0f + __expf(-x)); }
static __device__ __forceinline__ float ftanh(float x) { return 2.0f / (1.0f + __expf(-2.0f*x)) - 1.0f; }
static __device__ __forceinline__ unsigned short f2bf(float f) {
    __hip_bfloat16 h = __float2bfloat16(f); return *reinterpret_cast<unsigned short*>(&h);
}

static __device__ __forceinline__ void async_copy16(const void* g, void* l) {
    __builtin_amdgcn_global_load_lds(
        (const __attribute__((address_space(1))) unsigned int*)g,
        (__attribute__((address_space(3))) unsigned int*)l, 16, 0, 0);
}

// ---------------- packed weight prep ----------------
// Column order: c = bx*128 + wc*64 + g*16 + rl ; unit j = bx*32 + wc*16 + rl ; gate g.
// GRU gates: 0=r, 1=z, 2=inn (x-only), 3=hn (h-only). Tree gates: 0=i, 1=o, 2=u, 3=f.
__global__ __launch_bounds__(256) void prep_w_kernel(
    const float* __restrict__ gwi, const float* __restrict__ gwh,
    const float* __restrict__ gbi, const float* __restrict__ gbh,
    const float* __restrict__ x1w, const float* __restrict__ x1b,
    const float* __restrict__ h1w, const float* __restrict__ h1b,
    const float* __restrict__ fx1w, const float* __restrict__ fx1b,
    const float* __restrict__ fh1w, const float* __restrict__ fh1b,
    const float* __restrict__ x2w, const float* __restrict__ x2b,
    const float* __restrict__ h2w, const float* __restrict__ h2b,
    const float* __restrict__ fx2w, const float* __restrict__ fx2b,
    const float* __restrict__ fh2w, const float* __restrict__ fh2b,
    __hip_bfloat16* __restrict__ Wx, __hip_bfloat16* __restrict__ Wh,
    float* __restrict__ bp)
{
    int z = blockIdx.z;
    int idx = blockIdx.x * 256 + threadIdx.x;      // < GCOLS*KCAT
    int c = idx / KCAT, k = idx - c * KCAT;
    int bx = c >> 7, wc = (c >> 6) & 1, g = (c >> 4) & 3, rl = c & 15;
    int j = bx*32 + wc*16 + rl;
    float v = 0.0f, bv = 0.0f;
    if (z == 0) {
        if (g <= 1) {
            int row = g*HH + j;
            v = (k < FF) ? gwi[row*FF + k] : gwh[row*HH + (k-FF)];
            bv = gbi[row] + gbh[row];
        } else if (g == 2) {
            int row = 2*HH + j;
            v = (k < FF) ? gwi[row*FF + k] : 0.0f;
            bv = gbi[row];
        } else {
            int row = 2*HH + j;
            v = (k < FF) ? 0.0f : gwh[row*HH + (k-FF)];
            bv = gbh[row];
        }
    } else {
        const float* xw  = (z==1)? x1w  : x2w;   const float* xb  = (z==1)? x1b  : x2b;
        const float* hw  = (z==1)? h1w  : h2w;   const float* hb_ = (z==1)? h1b  : h2b;
        const float* fxw = (z==1)? fx1w : fx2w;  const float* fxb = (z==1)? fx1b : fx2b;
        const float* fhw = (z==1)? fh1w : fh2w;  const float* fhb = (z==1)? fh1b : fh2b;
        if (g < 3) {
            int row = g*HH + j;
            v = (k < FF) ? xw[row*FF + k] : hw[row*HH + (k-FF)];
            bv = xb[row] + hb_[row];
        } else {
            v = (k < FF) ? fxw[j*FF + k] : fhw[j*HH + (k-FF)];
            bv = fxb[j] + fhb[j];
        }
    }
    if (k < FF) Wx[(size_t)z*GCOLS*FF + (size_t)c*FF + k] = __float2bfloat16(v);
    else        Wh[(size_t)z*GCOLS*HH + (size_t)c*HH + (k-FF)] = __float2bfloat16(v);
    if (k == 0) bp[z*GCOLS + c] = bv;
}

// ---------------- vectorized fp32 -> bf16 ----------------
__global__ __launch_bounds__(256) void f2b4_kernel(const float* __restrict__ s,
                                                   __hip_bfloat16* __restrict__ d, int n4)
{
    int i = blockIdx.x*256 + threadIdx.x;
    if (i >= n4) return;
    float4 v = ((const float4*)s)[i];
    ushort4 u = { f2bf(v.x), f2bf(v.y), f2bf(v.z), f2bf(v.w) };
    ((ushort4*)d)[i] = u;
}

// ---------------- plain MFMA GEMM (128x128 tile, simple 2-barrier loop) ----------------
#define BM 128
#define BN 128
#define BKK 32

__global__ __launch_bounds__(256) void gemm0_k(
    const __hip_bfloat16* __restrict__ Ab, size_t zA, int lda,
    const __hip_bfloat16* __restrict__ Wb, size_t zW, int K,
    const float* __restrict__ bias, size_t zB,
    float* __restrict__ C, size_t zC,
    __hip_bfloat16* __restrict__ C16, size_t zC16,
    int ldC, int M)
{
    const int z = blockIdx.z;
    const __hip_bfloat16* A = Ab + zA*z;
    const __hip_bfloat16* W = Wb + zW*z;

    __shared__ __align__(16) __hip_bfloat16 As[BM][BKK];
    __shared__ __align__(16) __hip_bfloat16 Bs[BN][BKK];

    const int tid  = threadIdx.x;
    const int lane = tid & 63;
    const int w    = tid >> 6;
    const int wr = w >> 1, wc = w & 1;
    const int rowBase = blockIdx.y * BM;
    const int colBase = blockIdx.x * BN;
    const int sRow = tid >> 2;
    const int sK   = (tid & 3) * 8;

    float4v acc[4][4];
    #pragma unroll
    for (int i = 0; i < 4; ++i)
        #pragma unroll
        for (int j = 0; j < 4; ++j)
            acc[i][j] = (float4v){0.f, 0.f, 0.f, 0.f};

    const int rl = lane & 15;
    const int kl = (lane >> 4) * 8;

    for (int kt = 0; kt < K; kt += BKK) {
        const int kk = kt + sK;
        #pragma unroll
        for (int i = 0; i < 2; ++i) {
            int gr = rowBase + i*64 + sRow;
            if (gr > M-1) gr = M-1;
            async_copy16(A + (size_t)gr*lda + kk, &As[i*64 + sRow][sK]);
        }
        #pragma unroll
        for (int i = 0; i < 2; ++i) {
            int r = i*64 + sRow;
            async_copy16(W + (size_t)(colBase + r)*K + kk, &Bs[r][sK]);
        }
        __syncthreads();

        short8 af[4], bfr[4];
        #pragma unroll
        for (int mi = 0; mi < 4; ++mi)
            af[mi] = *(const short8*)&As[wr*64 + mi*16 + rl][kl];
        #pragma unroll
        for (int ni = 0; ni < 4; ++ni)
            bfr[ni] = *(const short8*)&Bs[wc*64 + ni*16 + rl][kl];
        #pragma unroll
        for (int mi = 0; mi < 4; ++mi)
            #pragma unroll
            for (int ni = 0; ni < 4; ++ni)
                acc[mi][ni] = __builtin_amdgcn_mfma_f32_16x16x32_bf16(af[mi], bfr[ni], acc[mi][ni], 0, 0, 0);
        __syncthreads();
    }

    const int rq = (lane >> 4) * 4;
    float* Cz = C + zC*z;
    __hip_bfloat16* C16z = C16 ? (C16 + zC16*z) : nullptr;
    #pragma unroll
    for (int mi = 0; mi < 4; ++mi) {
        #pragma unroll
        for (int q = 0; q < 4; ++q) {
            int row = rowBase + wr*64 + mi*16 + rq + q;
            if (row >= M) continue;
            #pragma unroll
            for (int ni = 0; ni < 4; ++ni) {
                int col = colBase + wc*64 + ni*16 + rl;
                float v = acc[mi][ni][q];
                if (bias) v += bias[zB*z + col];
                Cz[(size_t)row*ldC + col] = v;
                if (C16z) C16z[(size_t)row*ldC + col] = __float2bfloat16(v);
            }
        }
    }
}

// ---------------- fused recurrent step ----------------
// 64x128 tile, 4-buffer depth-2 pipeline, 1 barrier/iter, XOR-swizzled LDS.
// gates = [x_t | h] @ [Wx | Wh]^T + bias, gate math fused in epilogue.
// MODE 1: GRU-only launch. MODE 3: combined (z=0 GRU, z=1,2 trees).
#define SBM 64
#define NT (KCAT/BKK)

struct StepSet {
    const __hip_bfloat16 *X, *Hin, *Wx, *Wh;
    const float *bp, *Sin;
    float *Sout;
    __hip_bfloat16 *Hout;
    int lda, xoff;
};

template<int MODE>
__global__ __launch_bounds__(256) void step_k(StepSet G, StepSet T)
{
    int mode, zt;
    if (MODE == 3 && blockIdx.z > 0) { mode = 2; zt = blockIdx.z - 1; }
    else { mode = 1; zt = 0; }
    const StepSet& S = (mode == 1) ? G : T;

    const __hip_bfloat16* X  = S.X   + (size_t)zt*TT*NN*FF;
    const __hip_bfloat16* Hi = S.Hin + (size_t)zt*NN*HH;
    const __hip_bfloat16* Wx = S.Wx  + (size_t)zt*GCOLS*FF;
    const __hip_bfloat16* Wh = S.Wh  + (size_t)zt*GCOLS*HH;
    const float* bp = S.bp + (size_t)zt*GCOLS;
    const float* Si = S.Sin + (size_t)zt*NN*HH;
    float* So = S.Sout + (size_t)zt*NN*HH;
    __hip_bfloat16* Ho = S.Hout + (size_t)zt*NN*HH;
    const int lda = S.lda, xoff = S.xoff;

    __shared__ __align__(16) __hip_bfloat16 As[4][SBM][BKK];
    __shared__ __align__(16) __hip_bfloat16 Bs[4][BN][BKK];

    const int tid  = threadIdx.x;
    const int lane = tid & 63;
    const int w    = tid >> 6;
    const int wr = w >> 1, wc = w & 1;
    const int rowBase = blockIdx.y * SBM;
    const int colBase = blockIdx.x * BN;

    // staging geometry: slot row = tid>>2, chunk = tid&3; source chunk XOR-swizzled
    const int sR  = tid >> 2;            // 0..63
    const int sC  = tid & 3;             // dest 16B chunk
    const int sSw = sC ^ ((sR >> 1) & 3);
    int gra = rowBase + sR; if (gra > NN-1) gra = NN-1;

    auto stage = [&](int buf, int kt) {
        if (kt < FF) {
            const int kk = kt + sSw*8;
            async_copy16(X  + (size_t)gra*lda + xoff + kk,          &As[buf][sR][sC*8]);
            async_copy16(Wx + (size_t)(colBase + sR)*FF + kk,       &Bs[buf][sR][sC*8]);
            async_copy16(Wx + (size_t)(colBase + 64 + sR)*FF + kk,  &Bs[buf][64 + sR][sC*8]);
        } else {
            const int kk = kt - FF + sSw*8;
            async_copy16(Hi + (size_t)gra*HH + kk,                  &As[buf][sR][sC*8]);
            async_copy16(Wh + (size_t)(colBase + sR)*HH + kk,       &Bs[buf][sR][sC*8]);
            async_copy16(Wh + (size_t)(colBase + 64 + sR)*HH + kk,  &Bs[buf][64 + sR][sC*8]);
        }
    };

    float4v acc[2][4];
    #pragma unroll
    for (int i = 0; i < 2; ++i)
        #pragma unroll
        for (int j = 0; j < 4; ++j)
            acc[i][j] = (float4v){0.f, 0.f, 0.f, 0.f};

    const int rl = lane & 15;
    const int dF = (lane >> 4) ^ ((rl >> 1) & 3);   // swizzled read chunk (rows ≡ rl mod 16)

    stage(0, 0);
    stage(1, BKK);

    for (int it = 0; it < NT; ++it) {
        if (it < NT-1) asm volatile("s_waitcnt vmcnt(3)" ::: "memory");
        else           asm volatile("s_waitcnt vmcnt(0)" ::: "memory");
        __builtin_amdgcn_sched_barrier(0);
        __builtin_amdgcn_s_barrier();
        __builtin_amdgcn_sched_barrier(0);
        if (it + 2 < NT) stage((it+2)&3, (it+2)*BKK);
        __builtin_amdgcn_sched_barrier(0);

        const int cur = it & 3;
        short8 af[2], bfr[4];
        #pragma unroll
        for (int mi = 0; mi < 2; ++mi)
            af[mi] = *(const short8*)&As[cur][wr*32 + mi*16 + rl][dF*8];

        const bool xph = (it*BKK) < FF;   // uniform per iter
        if (mode == 2) {
            #pragma unroll
            for (int ni = 0; ni < 4; ++ni)
                bfr[ni] = *(const short8*)&Bs[cur][wc*64 + ni*16 + rl][dF*8];
            asm volatile("s_waitcnt lgkmcnt(0)" ::: "memory");
            __builtin_amdgcn_sched_barrier(0);
            #pragma unroll
            for (int mi = 0; mi < 2; ++mi)
                #pragma unroll
                for (int ni = 0; ni < 4; ++ni)
                    acc[mi][ni] = __builtin_amdgcn_mfma_f32_16x16x32_bf16(af[mi], bfr[ni], acc[mi][ni], 0, 0, 0);
        } else if (xph) {
            #pragma unroll
            for (int ni = 0; ni < 3; ++ni)
                bfr[ni] = *(const short8*)&Bs[cur][wc*64 + ni*16 + rl][dF*8];
            asm volatile("s_waitcnt lgkmcnt(0)" ::: "memory");
            __builtin_amdgcn_sched_barrier(0);
            #pragma unroll
            for (int mi = 0; mi < 2; ++mi)
                #pragma unroll
                for (int ni = 0; ni < 3; ++ni)
                    acc[mi][ni] = __builtin_amdgcn_mfma_f32_16x16x32_bf16(af[mi], bfr[ni], acc[mi][ni], 0, 0, 0);
        } else {
            bfr[0] = *(const short8*)&Bs[cur][wc*64 + 0*16 + rl][dF*8];
            bfr[1] = *(const short8*)&Bs[cur][wc*64 + 1*16 + rl][dF*8];
            bfr[3] = *(const short8*)&Bs[cur][wc*64 + 3*16 + rl][dF*8];
            asm volatile("s_waitcnt lgkmcnt(0)" ::: "memory");
            __builtin_amdgcn_sched_barrier(0);
            #pragma unroll
            for (int mi = 0; mi < 2; ++mi) {
                acc[mi][0] = __builtin_amdgcn_mfma_f32_16x16x32_bf16(af[mi], bfr[0], acc[mi][0], 0, 0, 0);
                acc[mi][1] = __builtin_amdgcn_mfma_f32_16x16x32_bf16(af[mi], bfr[1], acc[mi][1], 0, 0, 0);
                acc[mi][3] = __builtin_amdgcn_mfma_f32_16x16x32_bf16(af[mi], bfr[3], acc[mi][3], 0, 0, 0);
            }
        }
    }

    const int rq = (lane >> 4) * 4;
    const int j  = (colBase >> 2) + wc*16 + rl;          // hidden unit index
    const int cb = colBase + wc*64 + rl;
    float b0 = bp[cb + 0];
    float b1 = bp[cb + 16];
    float b2 = bp[cb + 32];
    float b3 = bp[cb + 48];

    #pragma unroll
    for (int mi = 0; mi < 2; ++mi) {
        #pragma unroll
        for (int q = 0; q < 4; ++q) {
            int row = rowBase + wr*32 + mi*16 + rq + q;
            if (row >= NN) continue;
            float g0 = acc[mi][0][q] + b0;
            float g1 = acc[mi][1][q] + b1;
            float g2 = acc[mi][2][q] + b2;
            float g3 = acc[mi][3][q] + b3;
            size_t off = (size_t)row*HH + j;
            if (mode == 1) {
                float r  = fsig(g0), zz = fsig(g1);
                float n  = ftanh(g2 + r*g3);
                float hp = Si[off];
                float hn = (1.0f - zz)*n + zz*hp;
                So[off] = hn;
                Ho[off] = __float2bfloat16(hn);
            } else {
                float cp = Si[off];
                float cn = fsig(g0)*ftanh(g2) + fsig(g3)*cp;
                So[off] = cn;
                float hn = fsig(g1)*ftanh(cn);
                Ho[off] = __float2bfloat16(hn);
            }
        }
    }
}

// ---------------- GCN: CSR build + gather ----------------
__global__ __launch_bounds__(256) void count_kernel(const int* __restrict__ col, int* __restrict__ degi)
{
    int e = blockIdx.x*256 + threadIdx.x;
    if (e < EE) atomicAdd(&degi[col[e]], 1);
}

__global__ __launch_bounds__(1024) void scan_kernel(const int* __restrict__ degi,
    int* __restrict__ start, int* __restrict__ cursor, float* __restrict__ dinv)
{
    __shared__ int s[1024];
    int t = threadIdx.x;
    int v[4]; int sum = 0;
    #pragma unroll
    for (int i = 0; i < 4; ++i) {
        int idx = t*4 + i;
        v[i] = (idx < NN) ? degi[idx] : 0;
        sum += v[i];
    }
    s[t] = sum;
    __syncthreads();
    for (int d = 1; d < 1024; d <<= 1) {
        int x = (t >= d) ? s[t-d] : 0;
        __syncthreads();
        s[t] += x;
        __syncthreads();
    }
    int base = s[t] - sum;
    int run = 0;
    #pragma unroll
    for (int i = 0; i < 4; ++i) {
        int idx = t*4 + i;
        if (idx < NN) {
            int st = base + run;
            start[idx] = st;
            cursor[idx] = st;
            dinv[idx] = rsqrtf((float)v[i] + 1.0f);
        }
        run += v[i];
    }
    if (t == 1023) start[NN] = s[1023];
}

__global__ __launch_bounds__(256) void fill_kernel(const int* __restrict__ row,
    const int* __restrict__ col, int* __restrict__ cursor, int* __restrict__ esrc)
{
    int e = blockIdx.x*256 + threadIdx.x;
    if (e < EE) {
        int c = col[e];
        int pos = atomicAdd(&cursor[c], 1);
        esrc[pos] = row[e];
    }
}

__global__ __launch_bounds__(256) void gather_kernel(const float* __restrict__ xw,
    const int* __restrict__ esrc, const int* __restrict__ start,
    const float* __restrict__ dinv, const float* __restrict__ bias,
    float* __restrict__ mout, __hip_bfloat16* __restrict__ mout16, int relu)
{
    int wv = threadIdx.x >> 6, lane = threadIdx.x & 63;
    int n = blockIdx.x*4 + wv;
    if (n >= NN) return;
    float a[8] = {0.f,0.f,0.f,0.f,0.f,0.f,0.f,0.f};
    int s0 = start[n], s1 = start[n+1];
    float dn = dinv[n];
    for (int e = s0; e < s1; ++e) {
        int r = esrc[e];
        float nrm = dinv[r]*dn;
        const float4 v0 = *(const float4*)(xw + (size_t)r*D4 + lane*8);
        const float4 v1 = *(const float4*)(xw + (size_t)r*D4 + lane*8 + 4);
        a[0] += v0.x*nrm; a[1] += v0.y*nrm; a[2] += v0.z*nrm; a[3] += v0.w*nrm;
        a[4] += v1.x*nrm; a[5] += v1.y*nrm; a[6] += v1.z*nrm; a[7] += v1.w*nrm;
    }
    const float4 u0 = *(const float4*)(xw + (size_t)n*D4 + lane*8);
    const float4 u1 = *(const float4*)(xw + (size_t)n*D4 + lane*8 + 4);
    float dd = dn*dn;
    float su[8] = {u0.x,u0.y,u0.z,u0.w,u1.x,u1.y,u1.z,u1.w};
    #pragma unroll
    for (int i = 0; i < 8; ++i) {
        float vv = a[i] + su[i]*dd + bias[lane*8 + i];
        if (relu) vv = fmaxf(vv, 0.0f);
        mout[(size_t)n*D4 + lane*8 + i] = vv;
        if (mout16) mout16[(size_t)n*D4 + lane*8 + i] = __float2bfloat16(vv);
    }
}

// ---------------- head ----------------
__global__ __launch_bounds__(256) void final_kernel(const float* __restrict__ m,
    const float* __restrict__ w, const float* __restrict__ b, float* __restrict__ out)
{
    int wave = threadIdx.x >> 6;
    int lane = threadIdx.x & 63;
    int n = blockIdx.x*4 + wave;
    const float* row = m + (size_t)n*D4 + lane*8;
    float4 v0 = *(const float4*)(row);
    float4 v1 = *(const float4*)(row + 4);
    const float* w0 = w + lane*8;
    const float* w1 = w + D4 + lane*8;
    float4 u0 = *(const float4*)(w0); float4 u1 = *(const float4*)(w0 + 4);
    float4 t0 = *(const float4*)(w1); float4 t1 = *(const float4*)(w1 + 4);
    float a = v0.x*u0.x + v0.y*u0.y + v0.z*u0.z + v0.w*u0.w
            + v1.x*u1.x + v1.y*u1.y + v1.z*u1.z + v1.w*u1.w;
    float bb = v0.x*t0.x + v0.y*t0.y + v0.z*t0.z + v0.w*t0.w
             + v1.x*t1.x + v1.y*t1.y + v1.z*t1.z + v1.w*t1.w;
    #pragma unroll
    for (int s = 32; s; s >>= 1) { a += __shfl_xor(a, s); bb += __shfl_xor(bb, s); }
    if (lane == 0) {
        float l0 = a + b[0], l1 = bb + b[1];
        float mx = fmaxf(l0, l1);
        float e0 = expf(l0 - mx), e1 = expf(l1 - mx);
        float s = e0 + e1;
        out[n]      = e0 / s;
        out[NN + n] = e1 / s;
    }
}

extern "C" void kernel_launch(void* const* d_in, const int* in_sizes, int n_in,
                              void* d_out, int out_size, void* d_ws, size_t ws_size,
                              hipStream_t stream)
{
    const float* feat1 = (const float*)d_in[0];
    const float* feat2 = (const float*)d_in[1];
    const float* feat3 = (const float*)d_in[2];
    const float* feat4 = (const float*)d_in[3];
    const int*   eidx  = (const int*)d_in[4];
    const float* r1w = (const float*)d_in[25]; const float* r1b = (const float*)d_in[26];
    const float* r2w = (const float*)d_in[27]; const float* r2b = (const float*)d_in[28];
    const float* r3w = (const float*)d_in[29]; const float* r3b = (const float*)d_in[30];
    const float* r4w = (const float*)d_in[31]; const float* r4b = (const float*)d_in[32];
    const float* g0w = (const float*)d_in[33]; const float* g0b = (const float*)d_in[34];
    const float* g1w = (const float*)d_in[35]; const float* g1b = (const float*)d_in[36];
    const float* r7w = (const float*)d_in[37]; const float* r7b = (const float*)d_in[38];

    float* ws = (float*)d_ws;
    size_t o = 0;
    auto alloc = [&](size_t nfl) { float* p = ws + o; o += (nfl + 3) & ~(size_t)3; return p; };

    float* hf0 = alloc((size_t)NN*HH);
    float* cf0 = alloc((size_t)2*NN*HH);
    __hip_bfloat16* hb0 = (__hip_bfloat16*)alloc((size_t)3*NN*HH/2);
    size_t zeroFloats = o;                         // hf0, cf0, hb0 zeroed every call
    float* hf1 = alloc((size_t)NN*HH);
    float* cf1 = alloc((size_t)2*NN*HH);
    __hip_bfloat16* hb1 = (__hip_bfloat16*)alloc((size_t)3*NN*HH/2);
    __hip_bfloat16* xg  = (__hip_bfloat16*)alloc((size_t)TG*NN*FF/2);   // bf16 feat1 [n][t][f]
    __hip_bfloat16* xt  = (__hip_bfloat16*)alloc((size_t)2*TT*NN*FF/2); // bf16 feat2|3
    __hip_bfloat16* Wx  = (__hip_bfloat16*)alloc((size_t)3*GCOLS*FF/2);
    __hip_bfloat16* Wh  = (__hip_bfloat16*)alloc((size_t)3*GCOLS*HH/2);
    float* bp   = alloc(3*GCOLS);
    float* mbuf = alloc((size_t)NN*D4);
    float* xwb  = alloc((size_t)NN*D4);
    float* dinv = alloc(NN);
    __hip_bfloat16* mbf16 = (__hip_bfloat16*)alloc((size_t)NN*D4/2);
    __hip_bfloat16* f4b   = (__hip_bfloat16*)alloc((size_t)NN*D4/2);
    __hip_bfloat16* rw123 = (__hip_bfloat16*)alloc((size_t)3*128*HH/2);
    float* rb123 = alloc(3*128);
    __hip_bfloat16* r4w16 = (__hip_bfloat16*)alloc((size_t)128*D4/2);
    __hip_bfloat16* g0w16 = (__hip_bfloat16*)alloc((size_t)D4*D4/2);
    __hip_bfloat16* g1w16 = (__hip_bfloat16*)alloc((size_t)D4*D4/2);
    int* degi   = (int*)alloc(NN);
    int* start  = (int*)alloc(NN + 4);
    int* cursor = (int*)alloc(NN);
    int* esrc   = (int*)alloc(EE);

    float* hfp[2] = {hf0, hf1};
    float* cfp[2] = {cf0, cf1};
    __hip_bfloat16* hbp[2] = {hb0, hb1};

    hipMemsetAsync(hf0, 0, zeroFloats*sizeof(float), stream);
    hipMemsetAsync(degi, 0, NN*sizeof(int), stream);

    prep_w_kernel<<<dim3(3840,1,3),256,0,stream>>>(
        (const float*)d_in[5],(const float*)d_in[6],(const float*)d_in[7],(const float*)d_in[8],
        (const float*)d_in[9],(const float*)d_in[10],(const float*)d_in[11],(const float*)d_in[12],
        (const float*)d_in[13],(const float*)d_in[14],(const float*)d_in[15],(const float*)d_in[16],
        (const float*)d_in[17],(const float*)d_in[18],(const float*)d_in[19],(const float*)d_in[20],
        (const float*)d_in[21],(const float*)d_in[22],(const float*)d_in[23],(const float*)d_in[24],
        Wx, Wh, bp);

    f2b4_kernel<<<32000,256,0,stream>>>(feat1, xg, TG*NN*FF/4);
    f2b4_kernel<<<16000,256,0,stream>>>(feat2, xt, TT*NN*FF/4);
    f2b4_kernel<<<16000,256,0,stream>>>(feat3, xt + (size_t)TT*NN*FF, TT*NN*FF/4);
    f2b4_kernel<<<2000,256,0,stream>>>(feat4, f4b, NN*D4/4);
    f2b4_kernel<<<48,256,0,stream>>>(r1w, rw123, 128*HH/4);
    f2b4_kernel<<<48,256,0,stream>>>(r2w, rw123 + 128*HH, 128*HH/4);
    f2b4_kernel<<<48,256,0,stream>>>(r3w, rw123 + 2*128*HH, 128*HH/4);
    f2b4_kernel<<<64,256,0,stream>>>(r4w, r4w16, 128*D4/4);
    f2b4_kernel<<<256,256,0,stream>>>(g0w, g0w16, D4*D4/4);
    f2b4_kernel<<<256,256,0,stream>>>(g1w, g1w16, D4*D4/4);
    hipMemcpyAsync(rb123,       r1b, 128*sizeof(float), hipMemcpyDeviceToDevice, stream);
    hipMemcpyAsync(rb123 + 128, r2b, 128*sizeof(float), hipMemcpyDeviceToDevice, stream);
    hipMemcpyAsync(rb123 + 256, r3b, 128*sizeof(float), hipMemcpyDeviceToDevice, stream);

    count_kernel<<<250,256,0,stream>>>(eidx + EE, degi);
    scan_kernel<<<1,1024,0,stream>>>(degi, start, cursor, dinv);
    fill_kernel<<<250,256,0,stream>>>(eidx, eidx + EE, cursor, esrc);

    // ---- steps 0..15: GRU + both trees combined (z=3) ----
    for (int t = 0; t < TT; ++t) {
        int p = t & 1, q = p ^ 1;
        StepSet Gs = { xg, hbp[p], Wx, Wh, bp, hfp[p], hfp[q], hbp[q], TG*FF, t*FF };
        StepSet Ts = { xt, hbp[p] + (size_t)NN*HH,
                       Wx + (size_t)GCOLS*FF, Wh + (size_t)GCOLS*HH,
                       bp + GCOLS, cfp[p], cfp[q],
                       hbp[q] + (size_t)NN*HH, TT*FF, t*FF };
        step_k<3><<<dim3(GCOLS/BN, 63, 3),256,0,stream>>>(Gs, Ts);
    }
    // ---- steps 16..31: GRU only ----
    for (int t = TT; t < TG; ++t) {
        int p = t & 1, q = p ^ 1;
        StepSet Gs = { xg, hbp[p], Wx, Wh, bp, hfp[p], hfp[q], hbp[q], TG*FF, t*FF };
        step_k<1><<<dim3(GCOLS/BN, 63, 1),256,0,stream>>>(Gs, Gs);
    }
    // finals in hbp[0] slots 0..2 (TG, TT even)

    // ---- projections r1/r2/r3 batched (z=3), then r4 ----
    gemm0_k<<<dim3(1,32,3),256,0,stream>>>(
        hbp[0], (size_t)NN*HH, HH, rw123, (size_t)128*HH, HH, rb123, 128,
        mbuf, 128, mbf16, 128, D4, NN);
    gemm0_k<<<dim3(1,32,1),256,0,stream>>>(
        f4b, 0, D4, r4w16, 0, D4, r4b, 0,
        mbuf + 384, 0, mbf16 + 384, 0, D4, NN);

    // ---- GCN layer 0 (relu) ----
    gemm0_k<<<dim3(4,32,1),256,0,stream>>>(
        mbf16, 0, D4, g0w16, 0, D4, nullptr, 0,
        xwb, 0, nullptr, 0, D4, NN);
    gather_kernel<<<1000,256,0,stream>>>(xwb, esrc, start, dinv, g0b, mbuf, mbf16, 1);

    // ---- GCN layer 1 ----
    gemm0_k<<<dim3(4,32,1),256,0,stream>>>(
        mbf16, 0, D4, g1w16, 0, D4, nullptr, 0,
        xwb, 0, nullptr, 0, D4, NN);
    gather_kernel<<<1000,256,0,stream>>>(xwb, esrc, start, dinv, g1b, mbuf, nullptr, 0);

    final_kernel<<<1000,256,0,stream>>>(mbuf, r7w, r7b, (float*)d_out);
}

// Round 8
// 1546.535 us; speedup vs baseline: 1.0274x; 1.0274x over previous
//
#include <hip/hip_runtime.h>
#include <hip/hip_bf16.h>
#include <math.h>

#define NN 4000
#define TG 32
#define TT 16
#define FF 256
#define HH 384
#define GCOLS 1536
#define KCAT 640
#define EE 64000
#define D4 512

typedef __attribute__((ext_vector_type(8))) short short8;
typedef __attribute__((ext_vector_type(4))) float float4v;

static __device__ __forceinline__ float fsig(float x)  { return 1.0f / (1.0f + __expf(-x)); }
static __device__ __forceinline__ float ftanh(float x) { return 2.0f / (1.0f + __expf(-2.0f*x)) - 1.0f; }
static __device__ __forceinline__ unsigned short f2bf(float f) {
    __hip_bfloat16 h = __float2bfloat16(f); return *reinterpret_cast<unsigned short*>(&h);
}

static __device__ __forceinline__ void async_copy16(const void* g, void* l) {
    __builtin_amdgcn_global_load_lds(
        (const __attribute__((address_space(1))) unsigned int*)g,
        (__attribute__((address_space(3))) unsigned int*)l, 16, 0, 0);
}

// Bijective chunked XCD swizzle (m204): blocks with equal (w % 8) [same XCD]
// get consecutive logical tile ids -> per-XCD contiguous (z, row-range, all cols)
// working set that fits the 4 MB per-XCD L2.
static __device__ __forceinline__ void xcd_swz(int& bx, int& by, int& bz) {
    const int gx = gridDim.x, gy = gridDim.y;
    const int nwg = gx * gy * gridDim.z;
    const int w = (blockIdx.z * gy + blockIdx.y) * gx + blockIdx.x;
    const int q = nwg >> 3, r = nwg & 7;
    const int xcd = w & 7, i = w >> 3;
    const int L = (xcd < r ? xcd*(q+1) : r*(q+1) + (xcd - r)*q) + i;
    bx = L % gx; int rest = L / gx;
    by = rest % gy; bz = rest / gy;
}

// ---------------- packed weight prep ----------------
// Column order: c = bx*128 + wc*64 + g*16 + rl ; unit j = bx*32 + wc*16 + rl ; gate g.
// GRU gates: 0=r, 1=z, 2=inn (x-only), 3=hn (h-only). Tree gates: 0=i, 1=o, 2=u, 3=f.
__global__ __launch_bounds__(256) void prep_w_kernel(
    const float* __restrict__ gwi, const float* __restrict__ gwh,
    const float* __restrict__ gbi, const float* __restrict__ gbh,
    const float* __restrict__ x1w, const float* __restrict__ x1b,
    const float* __restrict__ h1w, const float* __restrict__ h1b,
    const float* __restrict__ fx1w, const float* __restrict__ fx1b,
    const float* __restrict__ fh1w, const float* __restrict__ fh1b,
    const float* __restrict__ x2w, const float* __restrict__ x2b,
    const float* __restrict__ h2w, const float* __restrict__ h2b,
    const float* __restrict__ fx2w, const float* __restrict__ fx2b,
    const float* __restrict__ fh2w, const float* __restrict__ fh2b,
    __hip_bfloat16* __restrict__ Wx, __hip_bfloat16* __restrict__ Wh,
    float* __restrict__ bp)
{
    int z = blockIdx.z;
    int idx = blockIdx.x * 256 + threadIdx.x;      // < GCOLS*KCAT
    int c = idx / KCAT, k = idx - c * KCAT;
    int bx = c >> 7, wc = (c >> 6) & 1, g = (c >> 4) & 3, rl = c & 15;
    int j = bx*32 + wc*16 + rl;
    float v = 0.0f, bv = 0.0f;
    if (z == 0) {
        if (g <= 1) {
            int row = g*HH + j;
            v = (k < FF) ? gwi[row*FF + k] : gwh[row*HH + (k-FF)];
            bv = gbi[row] + gbh[row];
        } else if (g == 2) {
            int row = 2*HH + j;
            v = (k < FF) ? gwi[row*FF + k] : 0.0f;
            bv = gbi[row];
        } else {
            int row = 2*HH + j;
            v = (k < FF) ? 0.0f : gwh[row*HH + (k-FF)];
            bv = gbh[row];
        }
    } else {
        const float* xw  = (z==1)? x1w  : x2w;   const float* xb  = (z==1)? x1b  : x2b;
        const float* hw  = (z==1)? h1w  : h2w;   const float* hb_ = (z==1)? h1b  : h2b;
        const float* fxw = (z==1)? fx1w : fx2w;  const float* fxb = (z==1)? fx1b : fx2b;
        const float* fhw = (z==1)? fh1w : fh2w;  const float* fhb = (z==1)? fh1b : fh2b;
        if (g < 3) {
            int row = g*HH + j;
            v = (k < FF) ? xw[row*FF + k] : hw[row*HH + (k-FF)];
            bv = xb[row] + hb_[row];
        } else {
            v = (k < FF) ? fxw[j*FF + k] : fhw[j*HH + (k-FF)];
            bv = fxb[j] + fhb[j];
        }
    }
    if (k < FF) Wx[(size_t)z*GCOLS*FF + (size_t)c*FF + k] = __float2bfloat16(v);
    else        Wh[(size_t)z*GCOLS*HH + (size_t)c*HH + (k-FF)] = __float2bfloat16(v);
    if (k == 0) bp[z*GCOLS + c] = bv;
}

// ---------------- vectorized fp32 -> bf16 ----------------
__global__ __launch_bounds__(256) void f2b4_kernel(const float* __restrict__ s,
                                                   __hip_bfloat16* __restrict__ d, int n4)
{
    int i = blockIdx.x*256 + threadIdx.x;
    if (i >= n4) return;
    float4 v = ((const float4*)s)[i];
    ushort4 u = { f2bf(v.x), f2bf(v.y), f2bf(v.z), f2bf(v.w) };
    ((ushort4*)d)[i] = u;
}

// ---------------- plain MFMA GEMM (128x128 tile, simple 2-barrier loop) ----------------
#define BM 128
#define BN 128
#define BKK 32

__global__ __launch_bounds__(256) void gemm0_k(
    const __hip_bfloat16* __restrict__ Ab, size_t zA, int lda,
    const __hip_bfloat16* __restrict__ Wb, size_t zW, int K,
    const float* __restrict__ bias, size_t zB,
    float* __restrict__ C, size_t zC,
    __hip_bfloat16* __restrict__ C16, size_t zC16,
    int ldC, int M)
{
    const int z = blockIdx.z;
    const __hip_bfloat16* A = Ab + zA*z;
    const __hip_bfloat16* W = Wb + zW*z;

    __shared__ __align__(16) __hip_bfloat16 As[BM][BKK];
    __shared__ __align__(16) __hip_bfloat16 Bs[BN][BKK];

    const int tid  = threadIdx.x;
    const int lane = tid & 63;
    const int w    = tid >> 6;
    const int wr = w >> 1, wc = w & 1;
    const int rowBase = blockIdx.y * BM;
    const int colBase = blockIdx.x * BN;
    const int sRow = tid >> 2;
    const int sK   = (tid & 3) * 8;

    float4v acc[4][4];
    #pragma unroll
    for (int i = 0; i < 4; ++i)
        #pragma unroll
        for (int j = 0; j < 4; ++j)
            acc[i][j] = (float4v){0.f, 0.f, 0.f, 0.f};

    const int rl = lane & 15;
    const int kl = (lane >> 4) * 8;

    for (int kt = 0; kt < K; kt += BKK) {
        const int kk = kt + sK;
        #pragma unroll
        for (int i = 0; i < 2; ++i) {
            int gr = rowBase + i*64 + sRow;
            if (gr > M-1) gr = M-1;
            async_copy16(A + (size_t)gr*lda + kk, &As[i*64 + sRow][sK]);
        }
        #pragma unroll
        for (int i = 0; i < 2; ++i) {
            int r = i*64 + sRow;
            async_copy16(W + (size_t)(colBase + r)*K + kk, &Bs[r][sK]);
        }
        __syncthreads();

        short8 af[4], bfr[4];
        #pragma unroll
        for (int mi = 0; mi < 4; ++mi)
            af[mi] = *(const short8*)&As[wr*64 + mi*16 + rl][kl];
        #pragma unroll
        for (int ni = 0; ni < 4; ++ni)
            bfr[ni] = *(const short8*)&Bs[wc*64 + ni*16 + rl][kl];
        #pragma unroll
        for (int mi = 0; mi < 4; ++mi)
            #pragma unroll
            for (int ni = 0; ni < 4; ++ni)
                acc[mi][ni] = __builtin_amdgcn_mfma_f32_16x16x32_bf16(af[mi], bfr[ni], acc[mi][ni], 0, 0, 0);
        __syncthreads();
    }

    const int rq = (lane >> 4) * 4;
    float* Cz = C + zC*z;
    __hip_bfloat16* C16z = C16 ? (C16 + zC16*z) : nullptr;
    #pragma unroll
    for (int mi = 0; mi < 4; ++mi) {
        #pragma unroll
        for (int q = 0; q < 4; ++q) {
            int row = rowBase + wr*64 + mi*16 + rq + q;
            if (row >= M) continue;
            #pragma unroll
            for (int ni = 0; ni < 4; ++ni) {
                int col = colBase + wc*64 + ni*16 + rl;
                float v = acc[mi][ni][q];
                if (bias) v += bias[zB*z + col];
                Cz[(size_t)row*ldC + col] = v;
                if (C16z) C16z[(size_t)row*ldC + col] = __float2bfloat16(v);
            }
        }
    }
}

// ---------------- fused recurrent step ----------------
// 64x128 tile, 4-buffer depth-2 pipeline, 1 barrier/iter, XOR-swizzled LDS,
// bijective chunked XCD swizzle for L2 locality.
// MODE 1: GRU-only launch. MODE 3: combined (z=0 GRU, z=1,2 trees).
#define SBM 64
#define NT (KCAT/BKK)

struct StepSet {
    const __hip_bfloat16 *X, *Hin, *Wx, *Wh;
    const float *bp, *Sin;
    float *Sout;
    __hip_bfloat16 *Hout;
    int lda, xoff;
};

template<int MODE>
__global__ __launch_bounds__(256) void step_k(StepSet G, StepSet T)
{
    int bxi, byi, bzi;
    xcd_swz(bxi, byi, bzi);

    int mode, zt;
    if (MODE == 3 && bzi > 0) { mode = 2; zt = bzi - 1; }
    else { mode = 1; zt = 0; }
    const StepSet& S = (mode == 1) ? G : T;

    const __hip_bfloat16* X  = S.X   + (size_t)zt*TT*NN*FF;
    const __hip_bfloat16* Hi = S.Hin + (size_t)zt*NN*HH;
    const __hip_bfloat16* Wx = S.Wx  + (size_t)zt*GCOLS*FF;
    const __hip_bfloat16* Wh = S.Wh  + (size_t)zt*GCOLS*HH;
    const float* bp = S.bp + (size_t)zt*GCOLS;
    const float* Si = S.Sin + (size_t)zt*NN*HH;
    float* So = S.Sout + (size_t)zt*NN*HH;
    __hip_bfloat16* Ho = S.Hout + (size_t)zt*NN*HH;
    const int lda = S.lda, xoff = S.xoff;

    __shared__ __align__(16) __hip_bfloat16 As[4][SBM][BKK];
    __shared__ __align__(16) __hip_bfloat16 Bs[4][BN][BKK];

    const int tid  = threadIdx.x;
    const int lane = tid & 63;
    const int w    = tid >> 6;
    const int wr = w >> 1, wc = w & 1;
    const int rowBase = byi * SBM;
    const int colBase = bxi * BN;

    // staging geometry: slot row = tid>>2, chunk = tid&3; source chunk XOR-swizzled
    const int sR  = tid >> 2;            // 0..63
    const int sC  = tid & 3;             // dest 16B chunk
    const int sSw = sC ^ ((sR >> 1) & 3);
    int gra = rowBase + sR; if (gra > NN-1) gra = NN-1;

    auto stage = [&](int buf, int kt) {
        if (kt < FF) {
            const int kk = kt + sSw*8;
            async_copy16(X  + (size_t)gra*lda + xoff + kk,          &As[buf][sR][sC*8]);
            async_copy16(Wx + (size_t)(colBase + sR)*FF + kk,       &Bs[buf][sR][sC*8]);
            async_copy16(Wx + (size_t)(colBase + 64 + sR)*FF + kk,  &Bs[buf][64 + sR][sC*8]);
        } else {
            const int kk = kt - FF + sSw*8;
            async_copy16(Hi + (size_t)gra*HH + kk,                  &As[buf][sR][sC*8]);
            async_copy16(Wh + (size_t)(colBase + sR)*HH + kk,       &Bs[buf][sR][sC*8]);
            async_copy16(Wh + (size_t)(colBase + 64 + sR)*HH + kk,  &Bs[buf][64 + sR][sC*8]);
        }
    };

    float4v acc[2][4];
    #pragma unroll
    for (int i = 0; i < 2; ++i)
        #pragma unroll
        for (int j = 0; j < 4; ++j)
            acc[i][j] = (float4v){0.f, 0.f, 0.f, 0.f};

    const int rl = lane & 15;
    const int dF = (lane >> 4) ^ ((rl >> 1) & 3);   // swizzled read chunk (rows ≡ rl mod 16)

    stage(0, 0);
    stage(1, BKK);

    for (int it = 0; it < NT; ++it) {
        if (it < NT-1) asm volatile("s_waitcnt vmcnt(3)" ::: "memory");
        else           asm volatile("s_waitcnt vmcnt(0)" ::: "memory");
        __builtin_amdgcn_sched_barrier(0);
        __builtin_amdgcn_s_barrier();
        __builtin_amdgcn_sched_barrier(0);
        if (it + 2 < NT) stage((it+2)&3, (it+2)*BKK);
        __builtin_amdgcn_sched_barrier(0);

        const int cur = it & 3;
        short8 af[2], bfr[4];
        #pragma unroll
        for (int mi = 0; mi < 2; ++mi)
            af[mi] = *(const short8*)&As[cur][wr*32 + mi*16 + rl][dF*8];

        const bool xph = (it*BKK) < FF;   // uniform per iter
        if (mode == 2) {
            #pragma unroll
            for (int ni = 0; ni < 4; ++ni)
                bfr[ni] = *(const short8*)&Bs[cur][wc*64 + ni*16 + rl][dF*8];
            asm volatile("s_waitcnt lgkmcnt(0)" ::: "memory");
            __builtin_amdgcn_sched_barrier(0);
            #pragma unroll
            for (int mi = 0; mi < 2; ++mi)
                #pragma unroll
                for (int ni = 0; ni < 4; ++ni)
                    acc[mi][ni] = __builtin_amdgcn_mfma_f32_16x16x32_bf16(af[mi], bfr[ni], acc[mi][ni], 0, 0, 0);
        } else if (xph) {
            #pragma unroll
            for (int ni = 0; ni < 3; ++ni)
                bfr[ni] = *(const short8*)&Bs[cur][wc*64 + ni*16 + rl][dF*8];
            asm volatile("s_waitcnt lgkmcnt(0)" ::: "memory");
            __builtin_amdgcn_sched_barrier(0);
            #pragma unroll
            for (int mi = 0; mi < 2; ++mi)
                #pragma unroll
                for (int ni = 0; ni < 3; ++ni)
                    acc[mi][ni] = __builtin_amdgcn_mfma_f32_16x16x32_bf16(af[mi], bfr[ni], acc[mi][ni], 0, 0, 0);
        } else {
            bfr[0] = *(const short8*)&Bs[cur][wc*64 + 0*16 + rl][dF*8];
            bfr[1] = *(const short8*)&Bs[cur][wc*64 + 1*16 + rl][dF*8];
            bfr[3] = *(const short8*)&Bs[cur][wc*64 + 3*16 + rl][dF*8];
            asm volatile("s_waitcnt lgkmcnt(0)" ::: "memory");
            __builtin_amdgcn_sched_barrier(0);
            #pragma unroll
            for (int mi = 0; mi < 2; ++mi) {
                acc[mi][0] = __builtin_amdgcn_mfma_f32_16x16x32_bf16(af[mi], bfr[0], acc[mi][0], 0, 0, 0);
                acc[mi][1] = __builtin_amdgcn_mfma_f32_16x16x32_bf16(af[mi], bfr[1], acc[mi][1], 0, 0, 0);
                acc[mi][3] = __builtin_amdgcn_mfma_f32_16x16x32_bf16(af[mi], bfr[3], acc[mi][3], 0, 0, 0);
            }
        }
    }

    const int rq = (lane >> 4) * 4;
    const int j  = (colBase >> 2) + wc*16 + rl;          // hidden unit index
    const int cb = colBase + wc*64 + rl;
    float b0 = bp[cb + 0];
    float b1 = bp[cb + 16];
    float b2 = bp[cb + 32];
    float b3 = bp[cb + 48];

    #pragma unroll
    for (int mi = 0; mi < 2; ++mi) {
        #pragma unroll
        for (int q = 0; q < 4; ++q) {
            int row = rowBase + wr*32 + mi*16 + rq + q;
            if (row >= NN) continue;
            float g0 = acc[mi][0][q] + b0;
            float g1 = acc[mi][1][q] + b1;
            float g2 = acc[mi][2][q] + b2;
            float g3 = acc[mi][3][q] + b3;
            size_t off = (size_t)row*HH + j;
            if (mode == 1) {
                float r  = fsig(g0), zz = fsig(g1);
                float n  = ftanh(g2 + r*g3);
                float hp = Si[off];
                float hn = (1.0f - zz)*n + zz*hp;
                So[off] = hn;
                Ho[off] = __float2bfloat16(hn);
            } else {
                float cp = Si[off];
                float cn = fsig(g0)*ftanh(g2) + fsig(g3)*cp;
                So[off] = cn;
                float hn = fsig(g1)*ftanh(cn);
                Ho[off] = __float2bfloat16(hn);
            }
        }
    }
}

// ---------------- GCN: CSR build + gather ----------------
__global__ __launch_bounds__(256) void count_kernel(const int* __restrict__ col, int* __restrict__ degi)
{
    int e = blockIdx.x*256 + threadIdx.x;
    if (e < EE) atomicAdd(&degi[col[e]], 1);
}

__global__ __launch_bounds__(1024) void scan_kernel(const int* __restrict__ degi,
    int* __restrict__ start, int* __restrict__ cursor, float* __restrict__ dinv)
{
    __shared__ int s[1024];
    int t = threadIdx.x;
    int v[4]; int sum = 0;
    #pragma unroll
    for (int i = 0; i < 4; ++i) {
        int idx = t*4 + i;
        v[i] = (idx < NN) ? degi[idx] : 0;
        sum += v[i];
    }
    s[t] = sum;
    __syncthreads();
    for (int d = 1; d < 1024; d <<= 1) {
        int x = (t >= d) ? s[t-d] : 0;
        __syncthreads();
        s[t] += x;
        __syncthreads();
    }
    int base = s[t] - sum;
    int run = 0;
    #pragma unroll
    for (int i = 0; i < 4; ++i) {
        int idx = t*4 + i;
        if (idx < NN) {
            int st = base + run;
            start[idx] = st;
            cursor[idx] = st;
            dinv[idx] = rsqrtf((float)v[i] + 1.0f);
        }
        run += v[i];
    }
    if (t == 1023) start[NN] = s[1023];
}

__global__ __launch_bounds__(256) void fill_kernel(const int* __restrict__ row,
    const int* __restrict__ col, int* __restrict__ cursor, int* __restrict__ esrc)
{
    int e = blockIdx.x*256 + threadIdx.x;
    if (e < EE) {
        int c = col[e];
        int pos = atomicAdd(&cursor[c], 1);
        esrc[pos] = row[e];
    }
}

__global__ __launch_bounds__(256) void gather_kernel(const float* __restrict__ xw,
    const int* __restrict__ esrc, const int* __restrict__ start,
    const float* __restrict__ dinv, const float* __restrict__ bias,
    float* __restrict__ mout, __hip_bfloat16* __restrict__ mout16, int relu)
{
    int wv = threadIdx.x >> 6, lane = threadIdx.x & 63;
    int n = blockIdx.x*4 + wv;
    if (n >= NN) return;
    float a[8] = {0.f,0.f,0.f,0.f,0.f,0.f,0.f,0.f};
    int s0 = start[n], s1 = start[n+1];
    float dn = dinv[n];
    for (int e = s0; e < s1; ++e) {
        int r = esrc[e];
        float nrm = dinv[r]*dn;
        const float4 v0 = *(const float4*)(xw + (size_t)r*D4 + lane*8);
        const float4 v1 = *(const float4*)(xw + (size_t)r*D4 + lane*8 + 4);
        a[0] += v0.x*nrm; a[1] += v0.y*nrm; a[2] += v0.z*nrm; a[3] += v0.w*nrm;
        a[4] += v1.x*nrm; a[5] += v1.y*nrm; a[6] += v1.z*nrm; a[7] += v1.w*nrm;
    }
    const float4 u0 = *(const float4*)(xw + (size_t)n*D4 + lane*8);
    const float4 u1 = *(const float4*)(xw + (size_t)n*D4 + lane*8 + 4);
    float dd = dn*dn;
    float su[8] = {u0.x,u0.y,u0.z,u0.w,u1.x,u1.y,u1.z,u1.w};
    #pragma unroll
    for (int i = 0; i < 8; ++i) {
        float vv = a[i] + su[i]*dd + bias[lane*8 + i];
        if (relu) vv = fmaxf(vv, 0.0f);
        mout[(size_t)n*D4 + lane*8 + i] = vv;
        if (mout16) mout16[(size_t)n*D4 + lane*8 + i] = __float2bfloat16(vv);
    }
}

// ---------------- head ----------------
__global__ __launch_bounds__(256) void final_kernel(const float* __restrict__ m,
    const float* __restrict__ w, const float* __restrict__ b, float* __restrict__ out)
{
    int wave = threadIdx.x >> 6;
    int lane = threadIdx.x & 63;
    int n = blockIdx.x*4 + wave;
    const float* row = m + (size_t)n*D4 + lane*8;
    float4 v0 = *(const float4*)(row);
    float4 v1 = *(const float4*)(row + 4);
    const float* w0 = w + lane*8;
    const float* w1 = w + D4 + lane*8;
    float4 u0 = *(const float4*)(w0); float4 u1 = *(const float4*)(w0 + 4);
    float4 t0 = *(const float4*)(w1); float4 t1 = *(const float4*)(w1 + 4);
    float a = v0.x*u0.x + v0.y*u0.y + v0.z*u0.z + v0.w*u0.w
            + v1.x*u1.x + v1.y*u1.y + v1.z*u1.z + v1.w*u1.w;
    float bb = v0.x*t0.x + v0.y*t0.y + v0.z*t0.z + v0.w*t0.w
             + v1.x*t1.x + v1.y*t1.y + v1.z*t1.z + v1.w*t1.w;
    #pragma unroll
    for (int s = 32; s; s >>= 1) { a += __shfl_xor(a, s); bb += __shfl_xor(bb, s); }
    if (lane == 0) {
        float l0 = a + b[0], l1 = bb + b[1];
        float mx = fmaxf(l0, l1);
        float e0 = expf(l0 - mx), e1 = expf(l1 - mx);
        float s = e0 + e1;
        out[n]      = e0 / s;
        out[NN + n] = e1 / s;
    }
}

extern "C" void kernel_launch(void* const* d_in, const int* in_sizes, int n_in,
                              void* d_out, int out_size, void* d_ws, size_t ws_size,
                              hipStream_t stream)
{
    const float* feat1 = (const float*)d_in[0];
    const float* feat2 = (const float*)d_in[1];
    const float* feat3 = (const float*)d_in[2];
    const float* feat4 = (const float*)d_in[3];
    const int*   eidx  = (const int*)d_in[4];
    const float* r1w = (const float*)d_in[25]; const float* r1b = (const float*)d_in[26];
    const float* r2w = (const float*)d_in[27]; const float* r2b = (const float*)d_in[28];
    const float* r3w = (const float*)d_in[29]; const float* r3b = (const float*)d_in[30];
    const float* r4w = (const float*)d_in[31]; const float* r4b = (const float*)d_in[32];
    const float* g0w = (const float*)d_in[33]; const float* g0b = (const float*)d_in[34];
    const float* g1w = (const float*)d_in[35]; const float* g1b = (const float*)d_in[36];
    const float* r7w = (const float*)d_in[37]; const float* r7b = (const float*)d_in[38];

    float* ws = (float*)d_ws;
    size_t o = 0;
    auto alloc = [&](size_t nfl) { float* p = ws + o; o += (nfl + 3) & ~(size_t)3; return p; };

    float* hf0 = alloc((size_t)NN*HH);
    float* cf0 = alloc((size_t)2*NN*HH);
    __hip_bfloat16* hb0 = (__hip_bfloat16*)alloc((size_t)3*NN*HH/2);
    size_t zeroFloats = o;                         // hf0, cf0, hb0 zeroed every call
    float* hf1 = alloc((size_t)NN*HH);
    float* cf1 = alloc((size_t)2*NN*HH);
    __hip_bfloat16* hb1 = (__hip_bfloat16*)alloc((size_t)3*NN*HH/2);
    __hip_bfloat16* xg  = (__hip_bfloat16*)alloc((size_t)TG*NN*FF/2);   // bf16 feat1 [n][t][f]
    __hip_bfloat16* xt  = (__hip_bfloat16*)alloc((size_t)2*TT*NN*FF/2); // bf16 feat2|3
    __hip_bfloat16* Wx  = (__hip_bfloat16*)alloc((size_t)3*GCOLS*FF/2);
    __hip_bfloat16* Wh  = (__hip_bfloat16*)alloc((size_t)3*GCOLS*HH/2);
    float* bp   = alloc(3*GCOLS);
    float* mbuf = alloc((size_t)NN*D4);
    float* xwb  = alloc((size_t)NN*D4);
    float* dinv = alloc(NN);
    __hip_bfloat16* mbf16 = (__hip_bfloat16*)alloc((size_t)NN*D4/2);
    __hip_bfloat16* f4b   = (__hip_bfloat16*)alloc((size_t)NN*D4/2);
    __hip_bfloat16* rw123 = (__hip_bfloat16*)alloc((size_t)3*128*HH/2);
    float* rb123 = alloc(3*128);
    __hip_bfloat16* r4w16 = (__hip_bfloat16*)alloc((size_t)128*D4/2);
    __hip_bfloat16* g0w16 = (__hip_bfloat16*)alloc((size_t)D4*D4/2);
    __hip_bfloat16* g1w16 = (__hip_bfloat16*)alloc((size_t)D4*D4/2);
    int* degi   = (int*)alloc(NN);
    int* start  = (int*)alloc(NN + 4);
    int* cursor = (int*)alloc(NN);
    int* esrc   = (int*)alloc(EE);

    float* hfp[2] = {hf0, hf1};
    float* cfp[2] = {cf0, cf1};
    __hip_bfloat16* hbp[2] = {hb0, hb1};

    hipMemsetAsync(hf0, 0, zeroFloats*sizeof(float), stream);
    hipMemsetAsync(degi, 0, NN*sizeof(int), stream);

    prep_w_kernel<<<dim3(3840,1,3),256,0,stream>>>(
        (const float*)d_in[5],(const float*)d_in[6],(const float*)d_in[7],(const float*)d_in[8],
        (const float*)d_in[9],(const float*)d_in[10],(const float*)d_in[11],(const float*)d_in[12],
        (const float*)d_in[13],(const float*)d_in[14],(const float*)d_in[15],(const float*)d_in[16],
        (const float*)d_in[17],(const float*)d_in[18],(const float*)d_in[19],(const float*)d_in[20],
        (const float*)d_in[21],(const float*)d_in[22],(const float*)d_in[23],(const float*)d_in[24],
        Wx, Wh, bp);

    f2b4_kernel<<<32000,256,0,stream>>>(feat1, xg, TG*NN*FF/4);
    f2b4_kernel<<<16000,256,0,stream>>>(feat2, xt, TT*NN*FF/4);
    f2b4_kernel<<<16000,256,0,stream>>>(feat3, xt + (size_t)TT*NN*FF, TT*NN*FF/4);
    f2b4_kernel<<<2000,256,0,stream>>>(feat4, f4b, NN*D4/4);
    f2b4_kernel<<<48,256,0,stream>>>(r1w, rw123, 128*HH/4);
    f2b4_kernel<<<48,256,0,stream>>>(r2w, rw123 + 128*HH, 128*HH/4);
    f2b4_kernel<<<48,256,0,stream>>>(r3w, rw123 + 2*128*HH, 128*HH/4);
    f2b4_kernel<<<64,256,0,stream>>>(r4w, r4w16, 128*D4/4);
    f2b4_kernel<<<256,256,0,stream>>>(g0w, g0w16, D4*D4/4);
    f2b4_kernel<<<256,256,0,stream>>>(g1w, g1w16, D4*D4/4);
    hipMemcpyAsync(rb123,       r1b, 128*sizeof(float), hipMemcpyDeviceToDevice, stream);
    hipMemcpyAsync(rb123 + 128, r2b, 128*sizeof(float), hipMemcpyDeviceToDevice, stream);
    hipMemcpyAsync(rb123 + 256, r3b, 128*sizeof(float), hipMemcpyDeviceToDevice, stream);

    count_kernel<<<250,256,0,stream>>>(eidx + EE, degi);
    scan_kernel<<<1,1024,0,stream>>>(degi, start, cursor, dinv);
    fill_kernel<<<250,256,0,stream>>>(eidx, eidx + EE, cursor, esrc);

    // ---- steps 0..15: GRU + both trees combined (z=3) ----
    for (int t = 0; t < TT; ++t) {
        int p = t & 1, q = p ^ 1;
        StepSet Gs = { xg, hbp[p], Wx, Wh, bp, hfp[p], hfp[q], hbp[q], TG*FF, t*FF };
        StepSet Ts = { xt, hbp[p] + (size_t)NN*HH,
                       Wx + (size_t)GCOLS*FF, Wh + (size_t)GCOLS*HH,
                       bp + GCOLS, cfp[p], cfp[q],
                       hbp[q] + (size_t)NN*HH, TT*FF, t*FF };
        step_k<3><<<dim3(GCOLS/BN, 63, 3),256,0,stream>>>(Gs, Ts);
    }
    // ---- steps 16..31: GRU only ----
    for (int t = TT; t < TG; ++t) {
        int p = t & 1, q = p ^ 1;
        StepSet Gs = { xg, hbp[p], Wx, Wh, bp, hfp[p], hfp[q], hbp[q], TG*FF, t*FF };
        step_k<1><<<dim3(GCOLS/BN, 63, 1),256,0,stream>>>(Gs, Gs);
    }
    // finals in hbp[0] slots 0..2 (TG, TT even)

    // ---- projections r1/r2/r3 batched (z=3), then r4 ----
    gemm0_k<<<dim3(1,32,3),256,0,stream>>>(
        hbp[0], (size_t)NN*HH, HH, rw123, (size_t)128*HH, HH, rb123, 128,
        mbuf, 128, mbf16, 128, D4, NN);
    gemm0_k<<<dim3(1,32,1),256,0,stream>>>(
        f4b, 0, D4, r4w16, 0, D4, r4b, 0,
        mbuf + 384, 0, mbf16 + 384, 0, D4, NN);

    // ---- GCN layer 0 (relu) ----
    gemm0_k<<<dim3(4,32,1),256,0,stream>>>(
        mbf16, 0, D4, g0w16, 0, D4, nullptr, 0,
        xwb, 0, nullptr, 0, D4, NN);
    gather_kernel<<<1000,256,0,stream>>>(xwb, esrc, start, dinv, g0b, mbuf, mbf16, 1);

    // ---- GCN layer 1 ----
    gemm0_k<<<dim3(4,32,1),256,0,stream>>>(
        mbf16, 0, D4, g1w16, 0, D4, nullptr, 0,
        xwb, 0, nullptr, 0, D4, NN);
    gather_kernel<<<1000,256,0,stream>>>(xwb, esrc, start, dinv, g1b, mbuf, nullptr, 0);

    final_kernel<<<1000,256,0,stream>>>(mbuf, r7w, r7b, (float*)d_out);
}

// Round 9
// 1398.191 us; speedup vs baseline: 1.1364x; 1.1061x over previous
//
#include <hip/hip_runtime.h>
#include <hip/hip_bf16.h>
#include <math.h>

#define NN 4000
#define TG 32
#define TT 16
#define FF 256
#define HH 384
#define GCOLS 1536
#define KCAT 640
#define EE 64000
#define D4 512

typedef __attribute__((ext_vector_type(8))) short short8;
typedef __attribute__((ext_vector_type(4))) float float4v;

static __device__ __forceinline__ float fsig(float x)  { return 1.0f / (1.0f + __expf(-x)); }
static __device__ __forceinline__ float ftanh(float x) { return 2.0f / (1.0f + __expf(-2.0f*x)) - 1.0f; }
static __device__ __forceinline__ unsigned short f2bf(float f) {
    __hip_bfloat16 h = __float2bfloat16(f); return *reinterpret_cast<unsigned short*>(&h);
}

static __device__ __forceinline__ void async_copy16(const void* g, void* l) {
    __builtin_amdgcn_global_load_lds(
        (const __attribute__((address_space(1))) unsigned int*)g,
        (__attribute__((address_space(3))) unsigned int*)l, 16, 0, 0);
}

// Bijective chunked XCD swizzle (m204).
static __device__ __forceinline__ void xcd_swz(int& bx, int& by, int& bz) {
    const int gx = gridDim.x, gy = gridDim.y;
    const int nwg = gx * gy * gridDim.z;
    const int w = (blockIdx.z * gy + blockIdx.y) * gx + blockIdx.x;
    const int q = nwg >> 3, r = nwg & 7;
    const int xcd = w & 7, i = w >> 3;
    const int L = (xcd < r ? xcd*(q+1) : r*(q+1) + (xcd - r)*q) + i;
    bx = L % gx; int rest = L / gx;
    by = rest % gy; bz = rest / gy;
}

// ---------------- packed weight prep ----------------
// Column order: c = bx*128 + wc*64 + g*16 + rl ; unit j = bx*32 + wc*16 + rl ; gate g.
// GRU gates: 0=r, 1=z, 2=inn (x-only), 3=hn (h-only). Tree gates: 0=i, 1=o, 2=u, 3=f.
__global__ __launch_bounds__(256) void prep_w_kernel(
    const float* __restrict__ gwi, const float* __restrict__ gwh,
    const float* __restrict__ gbi, const float* __restrict__ gbh,
    const float* __restrict__ x1w, const float* __restrict__ x1b,
    const float* __restrict__ h1w, const float* __restrict__ h1b,
    const float* __restrict__ fx1w, const float* __restrict__ fx1b,
    const float* __restrict__ fh1w, const float* __restrict__ fh1b,
    const float* __restrict__ x2w, const float* __restrict__ x2b,
    const float* __restrict__ h2w, const float* __restrict__ h2b,
    const float* __restrict__ fx2w, const float* __restrict__ fx2b,
    const float* __restrict__ fh2w, const float* __restrict__ fh2b,
    __hip_bfloat16* __restrict__ Wx, __hip_bfloat16* __restrict__ Wh,
    float* __restrict__ bp)
{
    int z = blockIdx.z;
    int idx = blockIdx.x * 256 + threadIdx.x;      // < GCOLS*KCAT
    int c = idx / KCAT, k = idx - c * KCAT;
    int bx = c >> 7, wc = (c >> 6) & 1, g = (c >> 4) & 3, rl = c & 15;
    int j = bx*32 + wc*16 + rl;
    float v = 0.0f, bv = 0.0f;
    if (z == 0) {
        if (g <= 1) {
            int row = g*HH + j;
            v = (k < FF) ? gwi[row*FF + k] : gwh[row*HH + (k-FF)];
            bv = gbi[row] + gbh[row];
        } else if (g == 2) {
            int row = 2*HH + j;
            v = (k < FF) ? gwi[row*FF + k] : 0.0f;
            bv = gbi[row];
        } else {
            int row = 2*HH + j;
            v = (k < FF) ? 0.0f : gwh[row*HH + (k-FF)];
            bv = gbh[row];
        }
    } else {
        const float* xw  = (z==1)? x1w  : x2w;   const float* xb  = (z==1)? x1b  : x2b;
        const float* hw  = (z==1)? h1w  : h2w;   const float* hb_ = (z==1)? h1b  : h2b;
        const float* fxw = (z==1)? fx1w : fx2w;  const float* fxb = (z==1)? fx1b : fx2b;
        const float* fhw = (z==1)? fh1w : fh2w;  const float* fhb = (z==1)? fh1b : fh2b;
        if (g < 3) {
            int row = g*HH + j;
            v = (k < FF) ? xw[row*FF + k] : hw[row*HH + (k-FF)];
            bv = xb[row] + hb_[row];
        } else {
            v = (k < FF) ? fxw[j*FF + k] : fhw[j*HH + (k-FF)];
            bv = fxb[j] + fhb[j];
        }
    }
    if (k < FF) Wx[(size_t)z*GCOLS*FF + (size_t)c*FF + k] = __float2bfloat16(v);
    else        Wh[(size_t)z*GCOLS*HH + (size_t)c*HH + (k-FF)] = __float2bfloat16(v);
    if (k == 0) bp[z*GCOLS + c] = bv;
}

// ---------------- vectorized fp32 -> bf16 ----------------
__global__ __launch_bounds__(256) void f2b4_kernel(const float* __restrict__ s,
                                                   __hip_bfloat16* __restrict__ d, int n4)
{
    int i = blockIdx.x*256 + threadIdx.x;
    if (i >= n4) return;
    float4 v = ((const float4*)s)[i];
    ushort4 u = { f2bf(v.x), f2bf(v.y), f2bf(v.z), f2bf(v.w) };
    ((ushort4*)d)[i] = u;
}

// ---------------- plain MFMA GEMM (128x128 tile, simple 2-barrier loop) ----------------
#define BM 128
#define BN 128
#define BKK 32

__global__ __launch_bounds__(256) void gemm0_k(
    const __hip_bfloat16* __restrict__ Ab, size_t zA, int lda,
    const __hip_bfloat16* __restrict__ Wb, size_t zW, int K,
    const float* __restrict__ bias, size_t zB,
    float* __restrict__ C, size_t zC,
    __hip_bfloat16* __restrict__ C16, size_t zC16,
    int ldC, int M)
{
    const int z = blockIdx.z;
    const __hip_bfloat16* A = Ab + zA*z;
    const __hip_bfloat16* W = Wb + zW*z;

    __shared__ __align__(16) __hip_bfloat16 As[BM][BKK];
    __shared__ __align__(16) __hip_bfloat16 Bs[BN][BKK];

    const int tid  = threadIdx.x;
    const int lane = tid & 63;
    const int w    = tid >> 6;
    const int wr = w >> 1, wc = w & 1;
    const int rowBase = blockIdx.y * BM;
    const int colBase = blockIdx.x * BN;
    const int sRow = tid >> 2;
    const int sK   = (tid & 3) * 8;

    float4v acc[4][4];
    #pragma unroll
    for (int i = 0; i < 4; ++i)
        #pragma unroll
        for (int j = 0; j < 4; ++j)
            acc[i][j] = (float4v){0.f, 0.f, 0.f, 0.f};

    const int rl = lane & 15;
    const int kl = (lane >> 4) * 8;

    for (int kt = 0; kt < K; kt += BKK) {
        const int kk = kt + sK;
        #pragma unroll
        for (int i = 0; i < 2; ++i) {
            int gr = rowBase + i*64 + sRow;
            if (gr > M-1) gr = M-1;
            async_copy16(A + (size_t)gr*lda + kk, &As[i*64 + sRow][sK]);
        }
        #pragma unroll
        for (int i = 0; i < 2; ++i) {
            int r = i*64 + sRow;
            async_copy16(W + (size_t)(colBase + r)*K + kk, &Bs[r][sK]);
        }
        __syncthreads();

        short8 af[4], bfr[4];
        #pragma unroll
        for (int mi = 0; mi < 4; ++mi)
            af[mi] = *(const short8*)&As[wr*64 + mi*16 + rl][kl];
        #pragma unroll
        for (int ni = 0; ni < 4; ++ni)
            bfr[ni] = *(const short8*)&Bs[wc*64 + ni*16 + rl][kl];
        #pragma unroll
        for (int mi = 0; mi < 4; ++mi)
            #pragma unroll
            for (int ni = 0; ni < 4; ++ni)
                acc[mi][ni] = __builtin_amdgcn_mfma_f32_16x16x32_bf16(af[mi], bfr[ni], acc[mi][ni], 0, 0, 0);
        __syncthreads();
    }

    const int rq = (lane >> 4) * 4;
    float* Cz = C + zC*z;
    __hip_bfloat16* C16z = C16 ? (C16 + zC16*z) : nullptr;
    #pragma unroll
    for (int mi = 0; mi < 4; ++mi) {
        #pragma unroll
        for (int q = 0; q < 4; ++q) {
            int row = rowBase + wr*64 + mi*16 + rq + q;
            if (row >= M) continue;
            #pragma unroll
            for (int ni = 0; ni < 4; ++ni) {
                int col = colBase + wc*64 + ni*16 + rl;
                float v = acc[mi][ni][q];
                if (bias) v += bias[zB*z + col];
                Cz[(size_t)row*ldC + col] = v;
                if (C16z) C16z[(size_t)row*ldC + col] = __float2bfloat16(v);
            }
        }
    }
}

// ---------------- step sets ----------------
struct StepSet {
    const __hip_bfloat16 *X, *Hin, *Wx, *Wh;
    const float *bp, *Sin;
    float *Sout;
    __hip_bfloat16 *Hout;
    int lda, xoff;
};

#define NT (KCAT/BKK)

// ---------------- GRU step: 64x128 tile, 4-buffer depth-2, 1 barrier/iter ----------------
#define SBM 64

__global__ __launch_bounds__(256) void step_k(StepSet S)
{
    int bxi, byi, bzi;
    xcd_swz(bxi, byi, bzi);

    const __hip_bfloat16* X  = S.X;
    const __hip_bfloat16* Hi = S.Hin;
    const __hip_bfloat16* Wx = S.Wx;
    const __hip_bfloat16* Wh = S.Wh;
    const float* bp = S.bp;
    const float* Si = S.Sin;
    float* So = S.Sout;
    __hip_bfloat16* Ho = S.Hout;
    const int lda = S.lda, xoff = S.xoff;

    __shared__ __align__(16) __hip_bfloat16 As[4][SBM][BKK];
    __shared__ __align__(16) __hip_bfloat16 Bs[4][BN][BKK];

    const int tid  = threadIdx.x;
    const int lane = tid & 63;
    const int w    = tid >> 6;
    const int wr = w >> 1, wc = w & 1;
    const int rowBase = byi * SBM;
    const int colBase = bxi * BN;

    const int sR  = tid >> 2;
    const int sC  = tid & 3;
    const int sSw = sC ^ ((sR >> 1) & 3);
    int gra = rowBase + sR; if (gra > NN-1) gra = NN-1;

    auto stage = [&](int buf, int kt) {
        if (kt < FF) {
            const int kk = kt + sSw*8;
            async_copy16(X  + (size_t)gra*lda + xoff + kk,          &As[buf][sR][sC*8]);
            async_copy16(Wx + (size_t)(colBase + sR)*FF + kk,       &Bs[buf][sR][sC*8]);
            async_copy16(Wx + (size_t)(colBase + 64 + sR)*FF + kk,  &Bs[buf][64 + sR][sC*8]);
        } else {
            const int kk = kt - FF + sSw*8;
            async_copy16(Hi + (size_t)gra*HH + kk,                  &As[buf][sR][sC*8]);
            async_copy16(Wh + (size_t)(colBase + sR)*HH + kk,       &Bs[buf][sR][sC*8]);
            async_copy16(Wh + (size_t)(colBase + 64 + sR)*HH + kk,  &Bs[buf][64 + sR][sC*8]);
        }
    };

    float4v acc[2][4];
    #pragma unroll
    for (int i = 0; i < 2; ++i)
        #pragma unroll
        for (int j = 0; j < 4; ++j)
            acc[i][j] = (float4v){0.f, 0.f, 0.f, 0.f};

    const int rl = lane & 15;
    const int dF = (lane >> 4) ^ ((rl >> 1) & 3);

    stage(0, 0);
    stage(1, BKK);

    for (int it = 0; it < NT; ++it) {
        if (it < NT-1) asm volatile("s_waitcnt vmcnt(3)" ::: "memory");
        else           asm volatile("s_waitcnt vmcnt(0)" ::: "memory");
        __builtin_amdgcn_sched_barrier(0);
        __builtin_amdgcn_s_barrier();
        __builtin_amdgcn_sched_barrier(0);
        if (it + 2 < NT) stage((it+2)&3, (it+2)*BKK);
        __builtin_amdgcn_sched_barrier(0);

        const int cur = it & 3;
        short8 af[2], bfr[4];
        #pragma unroll
        for (int mi = 0; mi < 2; ++mi)
            af[mi] = *(const short8*)&As[cur][wr*32 + mi*16 + rl][dF*8];

        const bool xph = (it*BKK) < FF;   // uniform per iter
        if (xph) {
            #pragma unroll
            for (int ni = 0; ni < 3; ++ni)
                bfr[ni] = *(const short8*)&Bs[cur][wc*64 + ni*16 + rl][dF*8];
            asm volatile("s_waitcnt lgkmcnt(0)" ::: "memory");
            __builtin_amdgcn_sched_barrier(0);
            #pragma unroll
            for (int mi = 0; mi < 2; ++mi)
                #pragma unroll
                for (int ni = 0; ni < 3; ++ni)
                    acc[mi][ni] = __builtin_amdgcn_mfma_f32_16x16x32_bf16(af[mi], bfr[ni], acc[mi][ni], 0, 0, 0);
        } else {
            bfr[0] = *(const short8*)&Bs[cur][wc*64 + 0*16 + rl][dF*8];
            bfr[1] = *(const short8*)&Bs[cur][wc*64 + 1*16 + rl][dF*8];
            bfr[3] = *(const short8*)&Bs[cur][wc*64 + 3*16 + rl][dF*8];
            asm volatile("s_waitcnt lgkmcnt(0)" ::: "memory");
            __builtin_amdgcn_sched_barrier(0);
            #pragma unroll
            for (int mi = 0; mi < 2; ++mi) {
                acc[mi][0] = __builtin_amdgcn_mfma_f32_16x16x32_bf16(af[mi], bfr[0], acc[mi][0], 0, 0, 0);
                acc[mi][1] = __builtin_amdgcn_mfma_f32_16x16x32_bf16(af[mi], bfr[1], acc[mi][1], 0, 0, 0);
                acc[mi][3] = __builtin_amdgcn_mfma_f32_16x16x32_bf16(af[mi], bfr[3], acc[mi][3], 0, 0, 0);
            }
        }
    }

    const int rq = (lane >> 4) * 4;
    const int j  = (colBase >> 2) + wc*16 + rl;
    const int cb = colBase + wc*64 + rl;
    float b0 = bp[cb + 0];
    float b1 = bp[cb + 16];
    float b2 = bp[cb + 32];
    float b3 = bp[cb + 48];

    #pragma unroll
    for (int mi = 0; mi < 2; ++mi) {
        #pragma unroll
        for (int q = 0; q < 4; ++q) {
            int row = rowBase + wr*32 + mi*16 + rq + q;
            if (row >= NN) continue;
            float g0 = acc[mi][0][q] + b0;
            float g1 = acc[mi][1][q] + b1;
            float g2 = acc[mi][2][q] + b2;
            float g3 = acc[mi][3][q] + b3;
            size_t off = (size_t)row*HH + j;
            float r  = fsig(g0), zz = fsig(g1);
            float n  = ftanh(g2 + r*g3);
            float hp = Si[off];
            float hn = (1.0f - zz)*n + zz*hp;
            So[off] = hn;
            Ho[off] = __float2bfloat16(hn);
        }
    }
}

// ---------------- tree step: 128x128 tile, 3-buffer depth-2, 1 barrier/iter ----------------
// grid (12, 32, 2) = 768 blocks = exactly one resident generation (3 blocks/CU x 256 CU).
__global__ __launch_bounds__(256) void stepT_k(StepSet T)
{
    int bxi, byi, bzi;
    xcd_swz(bxi, byi, bzi);
    const int zt = bzi;

    const __hip_bfloat16* X  = T.X   + (size_t)zt*TT*NN*FF;
    const __hip_bfloat16* Hi = T.Hin + (size_t)zt*NN*HH;
    const __hip_bfloat16* Wx = T.Wx  + (size_t)zt*GCOLS*FF;
    const __hip_bfloat16* Wh = T.Wh  + (size_t)zt*GCOLS*HH;
    const float* bp = T.bp + (size_t)zt*GCOLS;
    const float* Si = T.Sin + (size_t)zt*NN*HH;
    float* So = T.Sout + (size_t)zt*NN*HH;
    __hip_bfloat16* Ho = T.Hout + (size_t)zt*NN*HH;
    const int lda = T.lda, xoff = T.xoff;

    __shared__ __align__(16) __hip_bfloat16 As[3][BM][BKK];
    __shared__ __align__(16) __hip_bfloat16 Bs[3][BN][BKK];

    const int tid  = threadIdx.x;
    const int lane = tid & 63;
    const int w    = tid >> 6;
    const int wr = w >> 1, wc = w & 1;
    const int rowBase = byi * BM;
    const int colBase = bxi * BN;

    const int sR  = tid >> 2;
    const int sC  = tid & 3;
    const int sSw = sC ^ ((sR >> 1) & 3);   // row-XOR invariant to +64 row offset
    int gra0 = rowBase + sR;      if (gra0 > NN-1) gra0 = NN-1;
    int gra1 = rowBase + 64 + sR; if (gra1 > NN-1) gra1 = NN-1;

    auto stage = [&](int buf, int kt) {
        if (kt < FF) {
            const int kk = kt + sSw*8;
            async_copy16(X  + (size_t)gra0*lda + xoff + kk,         &As[buf][sR][sC*8]);
            async_copy16(X  + (size_t)gra1*lda + xoff + kk,         &As[buf][64 + sR][sC*8]);
            async_copy16(Wx + (size_t)(colBase + sR)*FF + kk,       &Bs[buf][sR][sC*8]);
            async_copy16(Wx + (size_t)(colBase + 64 + sR)*FF + kk,  &Bs[buf][64 + sR][sC*8]);
        } else {
            const int kk = kt - FF + sSw*8;
            async_copy16(Hi + (size_t)gra0*HH + kk,                 &As[buf][sR][sC*8]);
            async_copy16(Hi + (size_t)gra1*HH + kk,                 &As[buf][64 + sR][sC*8]);
            async_copy16(Wh + (size_t)(colBase + sR)*HH + kk,       &Bs[buf][sR][sC*8]);
            async_copy16(Wh + (size_t)(colBase + 64 + sR)*HH + kk,  &Bs[buf][64 + sR][sC*8]);
        }
    };

    float4v acc[4][4];
    #pragma unroll
    for (int i = 0; i < 4; ++i)
        #pragma unroll
        for (int j = 0; j < 4; ++j)
            acc[i][j] = (float4v){0.f, 0.f, 0.f, 0.f};

    const int rl = lane & 15;
    const int dF = (lane >> 4) ^ ((rl >> 1) & 3);

    stage(0, 0);
    stage(1, BKK);
    int cur = 0, nx2 = 2;

    for (int it = 0; it < NT; ++it) {
        if (it < NT-1) asm volatile("s_waitcnt vmcnt(4)" ::: "memory");
        else           asm volatile("s_waitcnt vmcnt(0)" ::: "memory");
        __builtin_amdgcn_sched_barrier(0);
        __builtin_amdgcn_s_barrier();
        __builtin_amdgcn_sched_barrier(0);
        if (it + 2 < NT) stage(nx2, (it+2)*BKK);
        __builtin_amdgcn_sched_barrier(0);

        short8 af[4], bfr[4];
        #pragma unroll
        for (int mi = 0; mi < 4; ++mi)
            af[mi] = *(const short8*)&As[cur][wr*64 + mi*16 + rl][dF*8];
        #pragma unroll
        for (int ni = 0; ni < 4; ++ni)
            bfr[ni] = *(const short8*)&Bs[cur][wc*64 + ni*16 + rl][dF*8];
        asm volatile("s_waitcnt lgkmcnt(0)" ::: "memory");
        __builtin_amdgcn_sched_barrier(0);
        #pragma unroll
        for (int mi = 0; mi < 4; ++mi)
            #pragma unroll
            for (int ni = 0; ni < 4; ++ni)
                acc[mi][ni] = __builtin_amdgcn_mfma_f32_16x16x32_bf16(af[mi], bfr[ni], acc[mi][ni], 0, 0, 0);

        cur = (cur == 2) ? 0 : cur + 1;
        nx2 = (nx2 == 2) ? 0 : nx2 + 1;
    }

    const int rq = (lane >> 4) * 4;
    const int j  = (colBase >> 2) + wc*16 + rl;
    const int cb = colBase + wc*64 + rl;
    float b0 = bp[cb + 0];
    float b1 = bp[cb + 16];
    float b2 = bp[cb + 32];
    float b3 = bp[cb + 48];

    #pragma unroll
    for (int mi = 0; mi < 4; ++mi) {
        #pragma unroll
        for (int q = 0; q < 4; ++q) {
            int row = rowBase + wr*64 + mi*16 + rq + q;
            if (row >= NN) continue;
            float g0 = acc[mi][0][q] + b0;
            float g1 = acc[mi][1][q] + b1;
            float g2 = acc[mi][2][q] + b2;
            float g3 = acc[mi][3][q] + b3;
            size_t off = (size_t)row*HH + j;
            float cp = Si[off];
            float cn = fsig(g0)*ftanh(g2) + fsig(g3)*cp;
            So[off] = cn;
            float hn = fsig(g1)*ftanh(cn);
            Ho[off] = __float2bfloat16(hn);
        }
    }
}

// ---------------- GCN: CSR build + gather ----------------
__global__ __launch_bounds__(256) void count_kernel(const int* __restrict__ col, int* __restrict__ degi)
{
    int e = blockIdx.x*256 + threadIdx.x;
    if (e < EE) atomicAdd(&degi[col[e]], 1);
}

__global__ __launch_bounds__(1024) void scan_kernel(const int* __restrict__ degi,
    int* __restrict__ start, int* __restrict__ cursor, float* __restrict__ dinv)
{
    __shared__ int s[1024];
    int t = threadIdx.x;
    int v[4]; int sum = 0;
    #pragma unroll
    for (int i = 0; i < 4; ++i) {
        int idx = t*4 + i;
        v[i] = (idx < NN) ? degi[idx] : 0;
        sum += v[i];
    }
    s[t] = sum;
    __syncthreads();
    for (int d = 1; d < 1024; d <<= 1) {
        int x = (t >= d) ? s[t-d] : 0;
        __syncthreads();
        s[t] += x;
        __syncthreads();
    }
    int base = s[t] - sum;
    int run = 0;
    #pragma unroll
    for (int i = 0; i < 4; ++i) {
        int idx = t*4 + i;
        if (idx < NN) {
            int st = base + run;
            start[idx] = st;
            cursor[idx] = st;
            dinv[idx] = rsqrtf((float)v[i] + 1.0f);
        }
        run += v[i];
    }
    if (t == 1023) start[NN] = s[1023];
}

__global__ __launch_bounds__(256) void fill_kernel(const int* __restrict__ row,
    const int* __restrict__ col, int* __restrict__ cursor, int* __restrict__ esrc)
{
    int e = blockIdx.x*256 + threadIdx.x;
    if (e < EE) {
        int c = col[e];
        int pos = atomicAdd(&cursor[c], 1);
        esrc[pos] = row[e];
    }
}

__global__ __launch_bounds__(256) void gather_kernel(const float* __restrict__ xw,
    const int* __restrict__ esrc, const int* __restrict__ start,
    const float* __restrict__ dinv, const float* __restrict__ bias,
    float* __restrict__ mout, __hip_bfloat16* __restrict__ mout16, int relu)
{
    int wv = threadIdx.x >> 6, lane = threadIdx.x & 63;
    int n = blockIdx.x*4 + wv;
    if (n >= NN) return;
    float a[8] = {0.f,0.f,0.f,0.f,0.f,0.f,0.f,0.f};
    int s0 = start[n], s1 = start[n+1];
    float dn = dinv[n];
    for (int e = s0; e < s1; ++e) {
        int r = esrc[e];
        float nrm = dinv[r]*dn;
        const float4 v0 = *(const float4*)(xw + (size_t)r*D4 + lane*8);
        const float4 v1 = *(const float4*)(xw + (size_t)r*D4 + lane*8 + 4);
        a[0] += v0.x*nrm; a[1] += v0.y*nrm; a[2] += v0.z*nrm; a[3] += v0.w*nrm;
        a[4] += v1.x*nrm; a[5] += v1.y*nrm; a[6] += v1.z*nrm; a[7] += v1.w*nrm;
    }
    const float4 u0 = *(const float4*)(xw + (size_t)n*D4 + lane*8);
    const float4 u1 = *(const float4*)(xw + (size_t)n*D4 + lane*8 + 4);
    float dd = dn*dn;
    float su[8] = {u0.x,u0.y,u0.z,u0.w,u1.x,u1.y,u1.z,u1.w};
    #pragma unroll
    for (int i = 0; i < 8; ++i) {
        float vv = a[i] + su[i]*dd + bias[lane*8 + i];
        if (relu) vv = fmaxf(vv, 0.0f);
        mout[(size_t)n*D4 + lane*8 + i] = vv;
        if (mout16) mout16[(size_t)n*D4 + lane*8 + i] = __float2bfloat16(vv);
    }
}

// ---------------- head ----------------
__global__ __launch_bounds__(256) void final_kernel(const float* __restrict__ m,
    const float* __restrict__ w, const float* __restrict__ b, float* __restrict__ out)
{
    int wave = threadIdx.x >> 6;
    int lane = threadIdx.x & 63;
    int n = blockIdx.x*4 + wave;
    const float* row = m + (size_t)n*D4 + lane*8;
    float4 v0 = *(const float4*)(row);
    float4 v1 = *(const float4*)(row + 4);
    const float* w0 = w + lane*8;
    const float* w1 = w + D4 + lane*8;
    float4 u0 = *(const float4*)(w0); float4 u1 = *(const float4*)(w0 + 4);
    float4 t0 = *(const float4*)(w1); float4 t1 = *(const float4*)(w1 + 4);
    float a = v0.x*u0.x + v0.y*u0.y + v0.z*u0.z + v0.w*u0.w
            + v1.x*u1.x + v1.y*u1.y + v1.z*u1.z + v1.w*u1.w;
    float bb = v0.x*t0.x + v0.y*t0.y + v0.z*t0.z + v0.w*t0.w
             + v1.x*t1.x + v1.y*t1.y + v1.z*t1.z + v1.w*t1.w;
    #pragma unroll
    for (int s = 32; s; s >>= 1) { a += __shfl_xor(a, s); bb += __shfl_xor(bb, s); }
    if (lane == 0) {
        float l0 = a + b[0], l1 = bb + b[1];
        float mx = fmaxf(l0, l1);
        float e0 = expf(l0 - mx), e1 = expf(l1 - mx);
        float s = e0 + e1;
        out[n]      = e0 / s;
        out[NN + n] = e1 / s;
    }
}

extern "C" void kernel_launch(void* const* d_in, const int* in_sizes, int n_in,
                              void* d_out, int out_size, void* d_ws, size_t ws_size,
                              hipStream_t stream)
{
    const float* feat1 = (const float*)d_in[0];
    const float* feat2 = (const float*)d_in[1];
    const float* feat3 = (const float*)d_in[2];
    const float* feat4 = (const float*)d_in[3];
    const int*   eidx  = (const int*)d_in[4];
    const float* r1w = (const float*)d_in[25]; const float* r1b = (const float*)d_in[26];
    const float* r2w = (const float*)d_in[27]; const float* r2b = (const float*)d_in[28];
    const float* r3w = (const float*)d_in[29]; const float* r3b = (const float*)d_in[30];
    const float* r4w = (const float*)d_in[31]; const float* r4b = (const float*)d_in[32];
    const float* g0w = (const float*)d_in[33]; const float* g0b = (const float*)d_in[34];
    const float* g1w = (const float*)d_in[35]; const float* g1b = (const float*)d_in[36];
    const float* r7w = (const float*)d_in[37]; const float* r7b = (const float*)d_in[38];

    float* ws = (float*)d_ws;
    size_t o = 0;
    auto alloc = [&](size_t nfl) { float* p = ws + o; o += (nfl + 3) & ~(size_t)3; return p; };

    float* hf0 = alloc((size_t)NN*HH);
    float* cf0 = alloc((size_t)2*NN*HH);
    __hip_bfloat16* hb0 = (__hip_bfloat16*)alloc((size_t)3*NN*HH/2);
    size_t zeroFloats = o;                         // hf0, cf0, hb0 zeroed every call
    float* hf1 = alloc((size_t)NN*HH);
    float* cf1 = alloc((size_t)2*NN*HH);
    __hip_bfloat16* hb1 = (__hip_bfloat16*)alloc((size_t)3*NN*HH/2);
    __hip_bfloat16* xg  = (__hip_bfloat16*)alloc((size_t)TG*NN*FF/2);   // bf16 feat1 [n][t][f]
    __hip_bfloat16* xt  = (__hip_bfloat16*)alloc((size_t)2*TT*NN*FF/2); // bf16 feat2|3
    __hip_bfloat16* Wx  = (__hip_bfloat16*)alloc((size_t)3*GCOLS*FF/2);
    __hip_bfloat16* Wh  = (__hip_bfloat16*)alloc((size_t)3*GCOLS*HH/2);
    float* bp   = alloc(3*GCOLS);
    float* mbuf = alloc((size_t)NN*D4);
    float* xwb  = alloc((size_t)NN*D4);
    float* dinv = alloc(NN);
    __hip_bfloat16* mbf16 = (__hip_bfloat16*)alloc((size_t)NN*D4/2);
    __hip_bfloat16* f4b   = (__hip_bfloat16*)alloc((size_t)NN*D4/2);
    __hip_bfloat16* rw123 = (__hip_bfloat16*)alloc((size_t)3*128*HH/2);
    float* rb123 = alloc(3*128);
    __hip_bfloat16* r4w16 = (__hip_bfloat16*)alloc((size_t)128*D4/2);
    __hip_bfloat16* g0w16 = (__hip_bfloat16*)alloc((size_t)D4*D4/2);
    __hip_bfloat16* g1w16 = (__hip_bfloat16*)alloc((size_t)D4*D4/2);
    int* degi   = (int*)alloc(NN);
    int* start  = (int*)alloc(NN + 4);
    int* cursor = (int*)alloc(NN);
    int* esrc   = (int*)alloc(EE);

    float* hfp[2] = {hf0, hf1};
    float* cfp[2] = {cf0, cf1};
    __hip_bfloat16* hbp[2] = {hb0, hb1};

    hipMemsetAsync(hf0, 0, zeroFloats*sizeof(float), stream);
    hipMemsetAsync(degi, 0, NN*sizeof(int), stream);

    prep_w_kernel<<<dim3(3840,1,3),256,0,stream>>>(
        (const float*)d_in[5],(const float*)d_in[6],(const float*)d_in[7],(const float*)d_in[8],
        (const float*)d_in[9],(const float*)d_in[10],(const float*)d_in[11],(const float*)d_in[12],
        (const float*)d_in[13],(const float*)d_in[14],(const float*)d_in[15],(const float*)d_in[16],
        (const float*)d_in[17],(const float*)d_in[18],(const float*)d_in[19],(const float*)d_in[20],
        (const float*)d_in[21],(const float*)d_in[22],(const float*)d_in[23],(const float*)d_in[24],
        Wx, Wh, bp);

    f2b4_kernel<<<32000,256,0,stream>>>(feat1, xg, TG*NN*FF/4);
    f2b4_kernel<<<16000,256,0,stream>>>(feat2, xt, TT*NN*FF/4);
    f2b4_kernel<<<16000,256,0,stream>>>(feat3, xt + (size_t)TT*NN*FF, TT*NN*FF/4);
    f2b4_kernel<<<2000,256,0,stream>>>(feat4, f4b, NN*D4/4);
    f2b4_kernel<<<48,256,0,stream>>>(r1w, rw123, 128*HH/4);
    f2b4_kernel<<<48,256,0,stream>>>(r2w, rw123 + 128*HH, 128*HH/4);
    f2b4_kernel<<<48,256,0,stream>>>(r3w, rw123 + 2*128*HH, 128*HH/4);
    f2b4_kernel<<<64,256,0,stream>>>(r4w, r4w16, 128*D4/4);
    f2b4_kernel<<<256,256,0,stream>>>(g0w, g0w16, D4*D4/4);
    f2b4_kernel<<<256,256,0,stream>>>(g1w, g1w16, D4*D4/4);
    hipMemcpyAsync(rb123,       r1b, 128*sizeof(float), hipMemcpyDeviceToDevice, stream);
    hipMemcpyAsync(rb123 + 128, r2b, 128*sizeof(float), hipMemcpyDeviceToDevice, stream);
    hipMemcpyAsync(rb123 + 256, r3b, 128*sizeof(float), hipMemcpyDeviceToDevice, stream);

    count_kernel<<<250,256,0,stream>>>(eidx + EE, degi);
    scan_kernel<<<1,1024,0,stream>>>(degi, start, cursor, dinv);
    fill_kernel<<<250,256,0,stream>>>(eidx, eidx + EE, cursor, esrc);

    // ---- GRU: 32 steps, 756 blocks each (1 resident generation) ----
    for (int t = 0; t < TG; ++t) {
        int p = t & 1, q = p ^ 1;
        StepSet Gs = { xg, hbp[p], Wx, Wh, bp, hfp[p], hfp[q], hbp[q], TG*FF, t*FF };
        step_k<<<dim3(GCOLS/BN, 63, 1),256,0,stream>>>(Gs);
    }
    // ---- Trees: 16 steps, 128^2 tile, 768 blocks (1 resident generation) ----
    for (int t = 0; t < TT; ++t) {
        int p = t & 1, q = p ^ 1;
        StepSet Ts = { xt, hbp[p] + (size_t)NN*HH,
                       Wx + (size_t)GCOLS*FF, Wh + (size_t)GCOLS*HH,
                       bp + GCOLS, cfp[p], cfp[q],
                       hbp[q] + (size_t)NN*HH, TT*FF, t*FF };
        stepT_k<<<dim3(GCOLS/BN, 32, 2),256,0,stream>>>(Ts);
    }
    // finals in hbp[0] slots 0..2 (TG, TT even)

    // ---- projections r1/r2/r3 batched (z=3), then r4 ----
    gemm0_k<<<dim3(1,32,3),256,0,stream>>>(
        hbp[0], (size_t)NN*HH, HH, rw123, (size_t)128*HH, HH, rb123, 128,
        mbuf, 128, mbf16, 128, D4, NN);
    gemm0_k<<<dim3(1,32,1),256,0,stream>>>(
        f4b, 0, D4, r4w16, 0, D4, r4b, 0,
        mbuf + 384, 0, mbf16 + 384, 0, D4, NN);

    // ---- GCN layer 0 (relu) ----
    gemm0_k<<<dim3(4,32,1),256,0,stream>>>(
        mbf16, 0, D4, g0w16, 0, D4, nullptr, 0,
        xwb, 0, nullptr, 0, D4, NN);
    gather_kernel<<<1000,256,0,stream>>>(xwb, esrc, start, dinv, g0b, mbuf, mbf16, 1);

    // ---- GCN layer 1 ----
    gemm0_k<<<dim3(4,32,1),256,0,stream>>>(
        mbf16, 0, D4, g1w16, 0, D4, nullptr, 0,
        xwb, 0, nullptr, 0, D4, NN);
    gather_kernel<<<1000,256,0,stream>>>(xwb, esrc, start, dinv, g1b, mbuf, nullptr, 0);

    final_kernel<<<1000,256,0,stream>>>(mbuf, r7w, r7b, (float*)d_out);
}